// Round 6
// baseline (3589.480 us; speedup 1.0000x reference)
//
#include <hip/hip_runtime.h>
#include <math.h>

#define D 2048
#define BROWS 1024
#define NEL (D*BROWS)
#define NBLK 1024
#define NTHREADS_TOT (NBLK*256)

// GEMM tile: 64 (rows) x 128 (cols), GK=16, 256 threads, 4x8 acc
#define GM 64
#define GN 128
#define GK 16

__device__ __forceinline__ double blk_reduce(double v, double* sm) {
    const int t = threadIdx.x;
    sm[t] = v;
    __syncthreads();
    for (int s = 128; s > 0; s >>= 1) {
        if (t < s) sm[t] += sm[t + s];
        __syncthreads();
    }
    double r = sm[0];
    __syncthreads();
    return r;
}

// NT GEMM: out[i][j] = sum_k A[i,k]*B[j,k]
// mode 0: full-K, out = acc + I - (W + W^T) fused epilogue (builds M, R1-exact bits)
// mode 1: raw store, split-K=2 via blockIdx.z -> P0/P1 (R1-exact per-element k-order)
// Register-prefetch software pipeline, single LDS buffer, 2 blocks/CU.
__global__ __launch_bounds__(256, 2) void k_gemm(const float* __restrict__ A,
        const float* __restrict__ B, float* __restrict__ P0, float* __restrict__ P1,
        const float* __restrict__ Wadj, int ksz, int mode, const int* __restrict__ frz)
{
    if (frz && *frz) return;
    __shared__ float As[GK][GM + 4];
    __shared__ float Bs[GK][GN + 4];
    const int t  = threadIdx.x;
    const int tx = t & 15, ty = t >> 4;
    const int row0 = blockIdx.y * GM, col0 = blockIdx.x * GN;
    const int k0 = blockIdx.z * ksz;
    float* __restrict__ out = blockIdx.z ? P1 : P0;

    const int wr = t >> 2, wq = t & 3;   // stage coords: row wr, k-quad wq
    const float* pA  = A + (size_t)(row0 + wr) * D + (k0 + wq * 4);
    const float* pB0 = B + (size_t)(col0 + wr) * D + (k0 + wq * 4);
    const float* pB1 = B + (size_t)(col0 + 64 + wr) * D + (k0 + wq * 4);

    float acc[4][8];
    #pragma unroll
    for (int i = 0; i < 4; ++i)
        #pragma unroll
        for (int j = 0; j < 8; ++j) acc[i][j] = 0.0f;

    const int ntiles = ksz / GK;
    float4 ga  = *reinterpret_cast<const float4*>(pA);
    float4 gb0 = *reinterpret_cast<const float4*>(pB0);
    float4 gb1 = *reinterpret_cast<const float4*>(pB1);
    pA += GK; pB0 += GK; pB1 += GK;

    for (int tt = 0; tt < ntiles; ++tt) {
        As[wq*4+0][wr] = ga.x;  As[wq*4+1][wr] = ga.y;
        As[wq*4+2][wr] = ga.z;  As[wq*4+3][wr] = ga.w;
        Bs[wq*4+0][wr] = gb0.x; Bs[wq*4+1][wr] = gb0.y;
        Bs[wq*4+2][wr] = gb0.z; Bs[wq*4+3][wr] = gb0.w;
        Bs[wq*4+0][wr+64] = gb1.x; Bs[wq*4+1][wr+64] = gb1.y;
        Bs[wq*4+2][wr+64] = gb1.z; Bs[wq*4+3][wr+64] = gb1.w;
        __syncthreads();
        if (tt + 1 < ntiles) {   // prefetch next tile; latency hidden by FMAs below
            ga  = *reinterpret_cast<const float4*>(pA);
            gb0 = *reinterpret_cast<const float4*>(pB0);
            gb1 = *reinterpret_cast<const float4*>(pB1);
            pA += GK; pB0 += GK; pB1 += GK;
        }
        #pragma unroll
        for (int k = 0; k < GK; ++k) {
            float a[4], b[8];
            *reinterpret_cast<float4*>(&a[0]) = *reinterpret_cast<const float4*>(&As[k][ty*4]);
            *reinterpret_cast<float4*>(&b[0]) = *reinterpret_cast<const float4*>(&Bs[k][tx*4]);
            *reinterpret_cast<float4*>(&b[4]) = *reinterpret_cast<const float4*>(&Bs[k][64 + tx*4]);
            #pragma unroll
            for (int i = 0; i < 4; ++i)
                #pragma unroll
                for (int j = 0; j < 8; ++j)
                    acc[i][j] += a[i] * b[j];
        }
        __syncthreads();
    }

    #pragma unroll
    for (int i = 0; i < 4; ++i) {
        const int grow = row0 + ty*4 + i;
        float vv[8];
        #pragma unroll
        for (int j = 0; j < 8; ++j) vv[j] = acc[i][j];
        if (mode == 0) {
            #pragma unroll
            for (int j = 0; j < 8; ++j) {
                const int gcol = col0 + ((j < 4) ? (tx*4 + j) : (64 + tx*4 + j - 4));
                const float wsum = Wadj[(size_t)grow * D + gcol] + Wadj[(size_t)gcol * D + grow];
                vv[j] += (grow == gcol ? 1.0f : 0.0f) - wsum;
            }
        }
        float* orow = &out[(size_t)grow * D + col0];
        *reinterpret_cast<float4*>(&orow[tx*4]) =
            make_float4(vv[0], vv[1], vv[2], vv[3]);
        *reinterpret_cast<float4*>(&orow[64 + tx*4]) =
            make_float4(vv[4], vv[5], vv[6], vv[7]);
    }
}

// init: c=z=c0, u=0, partial sums; last block computes scal[0..2] (fused decide0)
__global__ __launch_bounds__(256) void k_init(const float* __restrict__ c0,
        float* __restrict__ c, float* __restrict__ z, float* __restrict__ u,
        double* __restrict__ partials, double* __restrict__ scal,
        int* __restrict__ counter)
{
    __shared__ double sm[256];
    __shared__ int islast;
    double sc = 0.0, s3 = 0.0;
    const int tid = blockIdx.x * 256 + threadIdx.x;
    const float4 zero4 = make_float4(0.f, 0.f, 0.f, 0.f);
    for (int i4 = tid; i4 < NEL/4; i4 += NTHREADS_TOT) {
        const float4 v4 = reinterpret_cast<const float4*>(c0)[i4];
        reinterpret_cast<float4*>(c)[i4] = v4;
        reinterpret_cast<float4*>(z)[i4] = v4;
        reinterpret_cast<float4*>(u)[i4] = zero4;
        const float va[4] = {v4.x, v4.y, v4.z, v4.w};
        #pragma unroll
        for (int L = 0; L < 4; ++L) {
            sc += (double)cosf(va[L]);
            s3 += (double)((va[L] * va[L]) * va[L]);
        }
    }
    const double tc = blk_reduce(sc, sm);
    const double t3 = blk_reduce(s3, sm);
    if (threadIdx.x == 0) {
        partials[blockIdx.x] = tc; partials[NBLK + blockIdx.x] = t3;
        __threadfence();
        islast = (atomicAdd(counter, 1) == NBLK - 1);
    }
    __syncthreads();
    if (!islast) return;
    __threadfence();
    const int t = threadIdx.x;
    const double a = partials[t] + partials[t+256] + partials[t+512] + partials[t+768];
    const double b = partials[NBLK+t] + partials[NBLK+t+256] + partials[NBLK+t+512] + partials[NBLK+t+768];
    const double tc2 = blk_reduce(a, sm);
    const double t32 = blk_reduce(b, sm);
    if (t == 0) {
        *counter = 0;
        const double pas = fabs(tc2 / (double)NEL);
        const double chi = t32 / (double)NEL;
        scal[0] = pas; scal[1] = -chi; scal[2] = chi;
    }
}

// fused candidate + speculative z/u commit + reductions + decide (last block)
__global__ __launch_bounds__(256) void k_elem_pp(const float* __restrict__ P0,
        const float* __restrict__ P1, const float* __restrict__ cc,
        float* __restrict__ cn, float* __restrict__ z, float* __restrict__ u,
        const float* __restrict__ lw, const float* __restrict__ lb,
        double* __restrict__ partials, int* __restrict__ frz,
        double* __restrict__ scal, int* __restrict__ sel,
        int* __restrict__ counter, int next_sel)
{
#pragma clang fp contract(off)
    if (*frz) return;
    __shared__ double sm[256];
    __shared__ int islast;
    double sc = 0.0, s3 = 0.0;
    const int tid = blockIdx.x * 256 + threadIdx.x;
    for (int i4 = tid; i4 < NEL/4; i4 += NTHREADS_TOT) {
        const int j4 = i4 & (D/4 - 1);
        const float4 p0 = reinterpret_cast<const float4*>(P0)[i4];
        const float4 p1 = reinterpret_cast<const float4*>(P1)[i4];
        const float4 cv4 = reinterpret_cast<const float4*>(cc)[i4];
        const float4 zv4 = reinterpret_cast<const float4*>(z)[i4];
        const float4 uv4 = reinterpret_cast<const float4*>(u)[i4];
        const float4 w4 = reinterpret_cast<const float4*>(lw)[j4];
        const float4 b4 = reinterpret_cast<const float4*>(lb)[j4];
        const float p0a[4] = {p0.x, p0.y, p0.z, p0.w};
        const float p1a[4] = {p1.x, p1.y, p1.z, p1.w};
        const float cva[4] = {cv4.x, cv4.y, cv4.z, cv4.w};
        const float zva[4] = {zv4.x, zv4.y, zv4.z, zv4.w};
        const float uva[4] = {uv4.x, uv4.y, uv4.z, uv4.w};
        const float w4a[4] = {w4.x, w4.y, w4.z, w4.w};
        const float b4a[4] = {b4.x, b4.y, b4.z, b4.w};
        float Rc[4], Rz[4], Ru[4];
        #pragma unroll
        for (int L = 0; L < 4; ++L) {
            const float cv = cva[L];
            const float uv = uva[L];
            const float g = (p0a[L] + p1a[L]) + ((cv - zva[L]) + uv);  // RHO = 1
            const float lim = 1.0f + 0.5f * fabsf(g);                  // COHESION + MU*|g|
            const float mn = fminf(fabsf(cv), lim);
            const float cy = (cv > 0.0f) ? mn : ((cv < 0.0f) ? -mn : 0.0f);
            const float cnv = (cy * w4a[L] + b4a[L]) - 0.1f * g;       // STEP = 0.1
            Rc[L] = cnv;
            const float zi = cnv + uv;
            float zm = fabsf(zi) - 0.1f;                               // LAM/RHO
            zm = fmaxf(zm, 0.0f);
            const float zn = (zi > 0.0f) ? zm : ((zi < 0.0f) ? -zm : 0.0f);
            Rz[L] = zn;
            Ru[L] = uv + (cnv - zn);
            sc += (double)cosf(cnv);
            s3 += (double)((cnv * cnv) * cnv);
        }
        reinterpret_cast<float4*>(cn)[i4] = make_float4(Rc[0], Rc[1], Rc[2], Rc[3]);
        reinterpret_cast<float4*>(z)[i4]  = make_float4(Rz[0], Rz[1], Rz[2], Rz[3]);
        reinterpret_cast<float4*>(u)[i4]  = make_float4(Ru[0], Ru[1], Ru[2], Ru[3]);
    }
    const double tc = blk_reduce(sc, sm);
    const double t3 = blk_reduce(s3, sm);
    if (threadIdx.x == 0) {
        partials[blockIdx.x] = tc; partials[NBLK + blockIdx.x] = t3;
        __threadfence();
        islast = (atomicAdd(counter, 1) == NBLK - 1);
    }
    __syncthreads();
    if (!islast) return;
    __threadfence();
    const int t = threadIdx.x;
    const double a = partials[t] + partials[t+256] + partials[t+512] + partials[t+768];
    const double b = partials[NBLK+t] + partials[NBLK+t+256] + partials[NBLK+t+512] + partials[NBLK+t+768];
    const double tc2 = blk_reduce(a, sm);
    const double t32 = blk_reduce(b, sm);
    if (t == 0) {
        *counter = 0;
        const double pas = fabs(tc2 / (double)NEL);
        const double drift = fabs(pas - scal[0]);
        const double chi = t32 / (double)NEL;
        const double score = -chi * exp(-drift / 0.05);            // ZETA
        const bool violation = drift > 0.05;
        const bool stable = (score - scal[1]) >= -0.1;             // TAU
        if (!violation && stable) { scal[0] = pas; scal[1] = score; *sel = next_sel; }
        else                      { *frz = 1; }   // carry pure: one reject freezes forever
    }
}

// legacy (no ping-pong) path kernels
__global__ __launch_bounds__(256) void k_elem(float* __restrict__ P0,
        const float* __restrict__ P1, const float* __restrict__ c,
        const float* __restrict__ z, const float* __restrict__ u,
        const float* __restrict__ lw, const float* __restrict__ lb,
        double* __restrict__ partials, const int* __restrict__ frz)
{
#pragma clang fp contract(off)
    if (*frz) return;
    __shared__ double sm[256];
    double sc = 0.0, s3 = 0.0;
    const int tid = blockIdx.x * 256 + threadIdx.x;
    for (int i = tid; i < NEL; i += NTHREADS_TOT) {
        const int j = i & (D - 1);
        const float cv = c[i];
        const float g = (P0[i] + P1[i]) + ((cv - z[i]) + u[i]);
        const float lim = 1.0f + 0.5f * fabsf(g);
        const float mn = fminf(fabsf(cv), lim);
        const float cy = (cv > 0.0f) ? mn : ((cv < 0.0f) ? -mn : 0.0f);
        const float cnv = (cy * lw[j] + lb[j]) - 0.1f * g;
        P0[i] = cnv;
        sc += (double)cosf(cnv);
        s3 += (double)((cnv * cnv) * cnv);
    }
    const double tc = blk_reduce(sc, sm);
    const double t3 = blk_reduce(s3, sm);
    if (threadIdx.x == 0) { partials[blockIdx.x] = tc; partials[NBLK + blockIdx.x] = t3; }
}

__global__ __launch_bounds__(256) void k_decide(const double* __restrict__ partials,
        double* __restrict__ scal, int* __restrict__ flag, int* __restrict__ frz,
        int* __restrict__ sel, int next_sel)
{
    __shared__ double sm[256];
    if (*frz) return;
    const int t = threadIdx.x;
    const double a = partials[t] + partials[t+256] + partials[t+512] + partials[t+768];
    const double b = partials[NBLK+t] + partials[NBLK+t+256] + partials[NBLK+t+512] + partials[NBLK+t+768];
    const double tc = blk_reduce(a, sm);
    const double t3 = blk_reduce(b, sm);
    if (t == 0) {
        const double pas = fabs(tc / (double)NEL);
        const double drift = fabs(pas - scal[0]);
        const double chi = t3 / (double)NEL;
        const double score = -chi * exp(-drift / 0.05);
        const bool violation = drift > 0.05;
        const bool stable = (score - scal[1]) >= -0.1;
        const int acc = (!violation && stable) ? 1 : 0;
        *flag = acc;
        if (acc) { scal[0] = pas; scal[1] = score; *sel = next_sel; }
        else     { *frz = 1; }
    }
}

__global__ __launch_bounds__(256) void k_commit(const float* __restrict__ cn,
        float* __restrict__ c, float* __restrict__ z, float* __restrict__ u,
        const int* __restrict__ flag)
{
#pragma clang fp contract(off)
    if (*flag == 0) return;
    const int tid = blockIdx.x * 256 + threadIdx.x;
    for (int i = tid; i < NEL; i += NTHREADS_TOT) {
        const float cnv = cn[i];
        const float uv = u[i];
        const float zi = cnv + uv;
        float zm = fabsf(zi) - 0.1f;
        zm = fmaxf(zm, 0.0f);
        const float zn = (zi > 0.0f) ? zm : ((zi < 0.0f) ? -zm : 0.0f);
        c[i] = cnv;
        z[i] = zn;
        u[i] = uv + (cnv - zn);
    }
}

__global__ __launch_bounds__(256) void k_final_rows(const float* __restrict__ c0,
        const float* __restrict__ cA, const float* __restrict__ cB,
        const int* __restrict__ sel, float* __restrict__ outp)
{
#pragma clang fp contract(off)
    __shared__ double sm[256];
    const float* __restrict__ c = (*sel) ? cB : cA;
    const int row = blockIdx.x;
    const size_t base = (size_t)row * D;
    float tv[8];
    double s1 = 0.0;
    #pragma unroll
    for (int s = 0; s < 8; ++s) {
        const int j = threadIdx.x + s * 256;
        const float s0 = c0[base + j];
        const float delta = c[base + j] - s0;
        const float sym = rintf(delta * 10.0f) / 10.0f;
        const float tval = s0 + sym;
        tv[s] = tval;
        s1 += (double)tval;
    }
    const double tot = blk_reduce(s1, sm);
    const float m = (float)(tot / (double)D);
    double s2 = 0.0;
    #pragma unroll
    for (int s = 0; s < 8; ++s) {
        const float dev = tv[s] - m;
        s2 += (double)(dev * dev);
    }
    const double tot2 = blk_reduce(s2, sm);
    const float n = sqrtf((float)tot2);
    const float scale = fminf(1.0f, 10.0f / (n + 1e-8f));
    #pragma unroll
    for (int s = 0; s < 8; ++s) {
        const int j = threadIdx.x + s * 256;
        outp[base + j] = m + (tv[s] - m) * scale;
    }
}

// global reductions over final c + status epilogue (last block)
__global__ __launch_bounds__(256) void k_final_glob(const float* __restrict__ c0,
        const float* __restrict__ cA, const float* __restrict__ cB,
        const int* __restrict__ sel, double* __restrict__ partials,
        const double* __restrict__ scal, float* __restrict__ outp,
        int* __restrict__ counter)
{
    __shared__ double sm[256];
    __shared__ int islast;
    const float* __restrict__ c = (*sel) ? cB : cA;
    double s3 = 0.0, sd = 0.0;
    const int tid = blockIdx.x * 256 + threadIdx.x;
    for (int i = tid; i < NEL; i += NTHREADS_TOT) {
        const float v = c[i];
        s3 += (double)((v * v) * v);
        const float d = v - c0[i];
        sd += (double)(d * d);
    }
    const double t3 = blk_reduce(s3, sm);
    const double td = blk_reduce(sd, sm);
    if (threadIdx.x == 0) {
        partials[blockIdx.x] = t3; partials[NBLK + blockIdx.x] = td;
        __threadfence();
        islast = (atomicAdd(counter, 1) == NBLK - 1);
    }
    __syncthreads();
    if (!islast) return;
    __threadfence();
    const int t = threadIdx.x;
    const double a = partials[t] + partials[t+256] + partials[t+512] + partials[t+768];
    const double b = partials[NBLK+t] + partials[NBLK+t+256] + partials[NBLK+t+512] + partials[NBLK+t+768];
    const double t32 = blk_reduce(a, sm);
    const double td2 = blk_reduce(b, sm);
    if (t == 0) {
        *counter = 0;
        const double chi_cur = t32 / (double)NEL;
        const double diff = sqrt(td2);
        const double chi_orig = scal[2];
        const int s_cur = (chi_cur > 0.0) - (chi_cur < 0.0);
        const int s_org = (chi_orig > 0.0) - (chi_orig < 0.0);
        int status;
        if (s_cur != s_org)   status = 2;
        else if (diff > 5.0)  status = 2;
        else if (diff > 1.0)  status = 1;
        else                  status = 0;
        outp[NEL] = (float)status;
    }
}

extern "C" void kernel_launch(void* const* d_in, const int* in_sizes, int n_in,
                              void* d_out, int out_size, void* d_ws, size_t ws_size,
                              hipStream_t stream)
{
    const float* c0 = (const float*)d_in[0];
    const float* W  = (const float*)d_in[1];
    const float* lw = (const float*)d_in[2];
    const float* lb = (const float*)d_in[3];
    float* outp = (float*)d_out;

    const size_t M4 = (size_t)D * D;    // 4M floats
    const size_t N4 = (size_t)NEL;      // 2M floats
    float* Mb = (float*)d_ws;
    float* region = Mb + M4;

    const size_t tail_bytes = (2 * NBLK + 8) * sizeof(double) + 8 * sizeof(int);
    const bool pp = ws_size >= (M4 + 6 * N4) * sizeof(float) + tail_bytes;

    float *cA, *cB, *z, *u, *P0, *P1;
    if (pp) { cA = region; cB = cA + N4; z = cB + N4; u = z + N4; P0 = u + N4; P1 = P0 + N4; }
    else    { cA = region; cB = cA;      z = cA + N4; u = z + N4; P0 = u + N4; P1 = P0 + N4; }
    double* partials = (double*)(P1 + N4);
    double* scal = partials + 2 * NBLK;
    int* flag = (int*)(scal + 8);
    int* frz  = flag + 1;
    int* sel  = frz + 1;
    int* counter = sel + 1;

    // zero flag/frz/sel/counter (graph-capture-safe stream op)
    hipMemsetAsync(flag, 0, 4 * sizeof(int), stream);

    // M = (W-I)(W^T-I) = W W^T + I - W - W^T, full-K fused epilogue (R1-exact bits)
    k_gemm<<<dim3(D / GN, D / GM, 1), 256, 0, stream>>>(W, W, Mb, Mb, W, D, 0, nullptr);
    k_init<<<NBLK, 256, 0, stream>>>(c0, cA, z, u, partials, scal, counter);

    for (int t = 0; t < 20; ++t) {
        const float* ccur = (pp && (t & 1)) ? cB : cA;
        float* cnxt = (pp && !(t & 1)) ? cB : cA;
        k_gemm<<<dim3(D / GN, BROWS / GM, 2), 256, 0, stream>>>(ccur, Mb, P0, P1, nullptr, D / 2, 1, frz);
        if (pp) {
            k_elem_pp<<<NBLK, 256, 0, stream>>>(P0, P1, ccur, cnxt, z, u, lw, lb,
                                                partials, frz, scal, sel, counter, (t + 1) & 1);
        } else {
            k_elem<<<NBLK, 256, 0, stream>>>(P0, P1, cA, z, u, lw, lb, partials, frz);
            k_decide<<<1, 256, 0, stream>>>(partials, scal, flag, frz, sel, 0);
            k_commit<<<NBLK, 256, 0, stream>>>(P0, cA, z, u, flag);
        }
    }

    k_final_rows<<<BROWS, 256, 0, stream>>>(c0, cA, cB, sel, outp);
    k_final_glob<<<NBLK, 256, 0, stream>>>(c0, cA, cB, sel, partials, scal, outp, counter);
}

// Round 7
// 2856.232 us; speedup vs baseline: 1.2567x; 1.2567x over previous
//
#include <hip/hip_runtime.h>
#include <math.h>

#define D 2048
#define BROWS 1024
#define NEL (D*BROWS)
#define NBLK 1024
#define NTHREADS_TOT (NBLK*256)

// GEMM tile: 64 (rows) x 128 (cols), GK=16, 256 threads, 4x8 acc,
// static double-buffered LDS + register prefetch, 1 barrier per k-tile.
#define GM 64
#define GN 128
#define GK 16

__device__ __forceinline__ double blk_reduce(double v, double* sm) {
    const int t = threadIdx.x;
    sm[t] = v;
    __syncthreads();
    for (int s = 128; s > 0; s >>= 1) {
        if (t < s) sm[t] += sm[t + s];
        __syncthreads();
    }
    double r = sm[0];
    __syncthreads();
    return r;
}

// NT GEMM: out[i][j] = sum_k A[i,k]*B[j,k]
// mode 0: full-K, out = acc + I - (W + W^T) fused epilogue (builds M, R1-exact bits)
// mode 1: raw store, split-K=2 via blockIdx.z -> P0/P1 (R1-exact per-element k-order)
__global__ __launch_bounds__(256, 2) void k_gemm(const float* __restrict__ A,
        const float* __restrict__ B, float* __restrict__ P0, float* __restrict__ P1,
        const float* __restrict__ Wadj, int ksz, int mode, const int* __restrict__ frz)
{
    if (frz && *frz) return;
    __shared__ float As[2][GK][GM + 4];
    __shared__ float Bs[2][GK][GN + 4];
    const int t  = threadIdx.x;
    const int tx = t & 15, ty = t >> 4;
    const int row0 = blockIdx.y * GM, col0 = blockIdx.x * GN;
    const int k0 = blockIdx.z * ksz;
    float* __restrict__ out = blockIdx.z ? P1 : P0;

    const int wr = t >> 2, wq = t & 3;   // stage coords: row wr, k-quad wq
    const float* pA  = A + (size_t)(row0 + wr) * D + (k0 + wq * 4);
    const float* pB0 = B + (size_t)(col0 + wr) * D + (k0 + wq * 4);
    const float* pB1 = B + (size_t)(col0 + 64 + wr) * D + (k0 + wq * 4);

    float acc[4][8];
    #pragma unroll
    for (int i = 0; i < 4; ++i)
        #pragma unroll
        for (int j = 0; j < 8; ++j) acc[i][j] = 0.0f;

    const int ntiles = ksz / GK;   // 64 or 128, always even
    float4 ga, gb0, gb1;

#define LOADR { \
    ga  = *reinterpret_cast<const float4*>(pA);  \
    gb0 = *reinterpret_cast<const float4*>(pB0); \
    gb1 = *reinterpret_cast<const float4*>(pB1); \
    pA += GK; pB0 += GK; pB1 += GK; }

#define STAGE(BUF) { \
    As[BUF][wq*4+0][wr] = ga.x;  As[BUF][wq*4+1][wr] = ga.y;  \
    As[BUF][wq*4+2][wr] = ga.z;  As[BUF][wq*4+3][wr] = ga.w;  \
    Bs[BUF][wq*4+0][wr] = gb0.x; Bs[BUF][wq*4+1][wr] = gb0.y; \
    Bs[BUF][wq*4+2][wr] = gb0.z; Bs[BUF][wq*4+3][wr] = gb0.w; \
    Bs[BUF][wq*4+0][wr+64] = gb1.x; Bs[BUF][wq*4+1][wr+64] = gb1.y; \
    Bs[BUF][wq*4+2][wr+64] = gb1.z; Bs[BUF][wq*4+3][wr+64] = gb1.w; }

#define COMPUTE(BUF) { \
    _Pragma("unroll") \
    for (int k = 0; k < GK; ++k) { \
        float a[4], b[8]; \
        *reinterpret_cast<float4*>(&a[0]) = *reinterpret_cast<const float4*>(&As[BUF][k][ty*4]); \
        *reinterpret_cast<float4*>(&b[0]) = *reinterpret_cast<const float4*>(&Bs[BUF][k][tx*4]); \
        *reinterpret_cast<float4*>(&b[4]) = *reinterpret_cast<const float4*>(&Bs[BUF][k][64 + tx*4]); \
        _Pragma("unroll") \
        for (int i = 0; i < 4; ++i) \
            _Pragma("unroll") \
            for (int j = 0; j < 8; ++j) \
                acc[i][j] += a[i] * b[j]; \
    } }

    LOADR;                 // tile 0
    STAGE(0);
    __syncthreads();

    for (int tt = 0; tt < ntiles; tt += 2) {
        LOADR;             // regs for tile tt+1 (always valid)
        COMPUTE(0);        // tile tt
        STAGE(1);          // vmcnt wait lands here, after the FMAs
        __syncthreads();
        if (tt + 2 < ntiles) {
            LOADR;         // regs for tile tt+2
            COMPUTE(1);    // tile tt+1
            STAGE(0);
            __syncthreads();
        } else {
            COMPUTE(1);    // final tile
        }
    }

#undef LOADR
#undef STAGE
#undef COMPUTE

    #pragma unroll
    for (int i = 0; i < 4; ++i) {
        const int grow = row0 + ty*4 + i;
        float vv[8];
        #pragma unroll
        for (int j = 0; j < 8; ++j) vv[j] = acc[i][j];
        if (mode == 0) {
            #pragma unroll
            for (int j = 0; j < 8; ++j) {
                const int gcol = col0 + ((j < 4) ? (tx*4 + j) : (64 + tx*4 + j - 4));
                const float wsum = Wadj[(size_t)grow * D + gcol] + Wadj[(size_t)gcol * D + grow];
                vv[j] += (grow == gcol ? 1.0f : 0.0f) - wsum;
            }
        }
        float* orow = &out[(size_t)grow * D + col0];
        *reinterpret_cast<float4*>(&orow[tx*4]) =
            make_float4(vv[0], vv[1], vv[2], vv[3]);
        *reinterpret_cast<float4*>(&orow[64 + tx*4]) =
            make_float4(vv[4], vv[5], vv[6], vv[7]);
    }
}

__global__ __launch_bounds__(256) void k_init(const float* __restrict__ c0,
        float* __restrict__ c, float* __restrict__ z, float* __restrict__ u,
        double* __restrict__ partials)
{
    __shared__ double sm[256];
    double sc = 0.0, s3 = 0.0;
    const int tid = blockIdx.x * 256 + threadIdx.x;
    const float4 zero4 = make_float4(0.f, 0.f, 0.f, 0.f);
    for (int i4 = tid; i4 < NEL/4; i4 += NTHREADS_TOT) {
        const float4 v4 = reinterpret_cast<const float4*>(c0)[i4];
        reinterpret_cast<float4*>(c)[i4] = v4;
        reinterpret_cast<float4*>(z)[i4] = v4;
        reinterpret_cast<float4*>(u)[i4] = zero4;
        const float va[4] = {v4.x, v4.y, v4.z, v4.w};
        #pragma unroll
        for (int L = 0; L < 4; ++L) {
            sc += (double)cosf(va[L]);
            s3 += (double)((va[L] * va[L]) * va[L]);
        }
    }
    const double tc = blk_reduce(sc, sm);
    const double t3 = blk_reduce(s3, sm);
    if (threadIdx.x == 0) { partials[blockIdx.x] = tc; partials[NBLK + blockIdx.x] = t3; }
}

__global__ __launch_bounds__(256) void k_decide0(const double* __restrict__ partials,
        double* __restrict__ scal, int* __restrict__ flag, int* __restrict__ frz,
        int* __restrict__ sel)
{
    __shared__ double sm[256];
    const int t = threadIdx.x;
    const double a = partials[t] + partials[t+256] + partials[t+512] + partials[t+768];
    const double b = partials[NBLK+t] + partials[NBLK+t+256] + partials[NBLK+t+512] + partials[NBLK+t+768];
    const double tc = blk_reduce(a, sm);
    const double t3 = blk_reduce(b, sm);
    if (t == 0) {
        const double pas = fabs(tc / (double)NEL);
        const double chi = t3 / (double)NEL;
        scal[0] = pas; scal[1] = -chi; scal[2] = chi;
        *flag = 0; *frz = 0; *sel = 0;
    }
}

// fused candidate + speculative z/u commit + reductions (ping-pong c), float4
__global__ __launch_bounds__(256) void k_elem_pp(const float* __restrict__ P0,
        const float* __restrict__ P1, const float* __restrict__ cc,
        float* __restrict__ cn, float* __restrict__ z, float* __restrict__ u,
        const float* __restrict__ lw, const float* __restrict__ lb,
        double* __restrict__ partials, const int* __restrict__ frz)
{
#pragma clang fp contract(off)
    if (*frz) return;
    __shared__ double sm[256];
    double sc = 0.0, s3 = 0.0;
    const int tid = blockIdx.x * 256 + threadIdx.x;
    for (int i4 = tid; i4 < NEL/4; i4 += NTHREADS_TOT) {
        const int j4 = i4 & (D/4 - 1);
        const float4 p0 = reinterpret_cast<const float4*>(P0)[i4];
        const float4 p1 = reinterpret_cast<const float4*>(P1)[i4];
        const float4 cv4 = reinterpret_cast<const float4*>(cc)[i4];
        const float4 zv4 = reinterpret_cast<const float4*>(z)[i4];
        const float4 uv4 = reinterpret_cast<const float4*>(u)[i4];
        const float4 w4 = reinterpret_cast<const float4*>(lw)[j4];
        const float4 b4 = reinterpret_cast<const float4*>(lb)[j4];
        const float p0a[4] = {p0.x, p0.y, p0.z, p0.w};
        const float p1a[4] = {p1.x, p1.y, p1.z, p1.w};
        const float cva[4] = {cv4.x, cv4.y, cv4.z, cv4.w};
        const float zva[4] = {zv4.x, zv4.y, zv4.z, zv4.w};
        const float uva[4] = {uv4.x, uv4.y, uv4.z, uv4.w};
        const float w4a[4] = {w4.x, w4.y, w4.z, w4.w};
        const float b4a[4] = {b4.x, b4.y, b4.z, b4.w};
        float Rc[4], Rz[4], Ru[4];
        #pragma unroll
        for (int L = 0; L < 4; ++L) {
            const float cv = cva[L];
            const float uv = uva[L];
            const float g = (p0a[L] + p1a[L]) + ((cv - zva[L]) + uv);  // RHO = 1
            const float lim = 1.0f + 0.5f * fabsf(g);                  // COHESION + MU*|g|
            const float mn = fminf(fabsf(cv), lim);
            const float cy = (cv > 0.0f) ? mn : ((cv < 0.0f) ? -mn : 0.0f);
            const float cnv = (cy * w4a[L] + b4a[L]) - 0.1f * g;       // STEP = 0.1
            Rc[L] = cnv;
            const float zi = cnv + uv;
            float zm = fabsf(zi) - 0.1f;                               // LAM/RHO
            zm = fmaxf(zm, 0.0f);
            const float zn = (zi > 0.0f) ? zm : ((zi < 0.0f) ? -zm : 0.0f);
            Rz[L] = zn;
            Ru[L] = uv + (cnv - zn);
            sc += (double)cosf(cnv);
            s3 += (double)((cnv * cnv) * cnv);
        }
        reinterpret_cast<float4*>(cn)[i4] = make_float4(Rc[0], Rc[1], Rc[2], Rc[3]);
        reinterpret_cast<float4*>(z)[i4]  = make_float4(Rz[0], Rz[1], Rz[2], Rz[3]);
        reinterpret_cast<float4*>(u)[i4]  = make_float4(Ru[0], Ru[1], Ru[2], Ru[3]);
    }
    const double tc = blk_reduce(sc, sm);
    const double t3 = blk_reduce(s3, sm);
    if (threadIdx.x == 0) { partials[blockIdx.x] = tc; partials[NBLK + blockIdx.x] = t3; }
}

// legacy (no ping-pong): candidate into P0, commit separately
__global__ __launch_bounds__(256) void k_elem(float* __restrict__ P0,
        const float* __restrict__ P1, const float* __restrict__ c,
        const float* __restrict__ z, const float* __restrict__ u,
        const float* __restrict__ lw, const float* __restrict__ lb,
        double* __restrict__ partials, const int* __restrict__ frz)
{
#pragma clang fp contract(off)
    if (*frz) return;
    __shared__ double sm[256];
    double sc = 0.0, s3 = 0.0;
    const int tid = blockIdx.x * 256 + threadIdx.x;
    for (int i = tid; i < NEL; i += NTHREADS_TOT) {
        const int j = i & (D - 1);
        const float cv = c[i];
        const float g = (P0[i] + P1[i]) + ((cv - z[i]) + u[i]);
        const float lim = 1.0f + 0.5f * fabsf(g);
        const float mn = fminf(fabsf(cv), lim);
        const float cy = (cv > 0.0f) ? mn : ((cv < 0.0f) ? -mn : 0.0f);
        const float cnv = (cy * lw[j] + lb[j]) - 0.1f * g;
        P0[i] = cnv;
        sc += (double)cosf(cnv);
        s3 += (double)((cnv * cnv) * cnv);
    }
    const double tc = blk_reduce(sc, sm);
    const double t3 = blk_reduce(s3, sm);
    if (threadIdx.x == 0) { partials[blockIdx.x] = tc; partials[NBLK + blockIdx.x] = t3; }
}

__global__ __launch_bounds__(256) void k_decide(const double* __restrict__ partials,
        double* __restrict__ scal, int* __restrict__ flag, int* __restrict__ frz,
        int* __restrict__ sel, int next_sel)
{
    __shared__ double sm[256];
    if (*frz) return;
    const int t = threadIdx.x;
    const double a = partials[t] + partials[t+256] + partials[t+512] + partials[t+768];
    const double b = partials[NBLK+t] + partials[NBLK+t+256] + partials[NBLK+t+512] + partials[NBLK+t+768];
    const double tc = blk_reduce(a, sm);
    const double t3 = blk_reduce(b, sm);
    if (t == 0) {
        const double pas = fabs(tc / (double)NEL);
        const double drift = fabs(pas - scal[0]);
        const double chi = t3 / (double)NEL;
        const double score = -chi * exp(-drift / 0.05);            // ZETA
        const bool violation = drift > 0.05;
        const bool stable = (score - scal[1]) >= -0.1;             // TAU
        const int acc = (!violation && stable) ? 1 : 0;
        *flag = acc;
        if (acc) { scal[0] = pas; scal[1] = score; *sel = next_sel; }
        else     { *frz = 1; }   // carry is pure: once rejected, rejected forever
    }
}

__global__ __launch_bounds__(256) void k_commit(const float* __restrict__ cn,
        float* __restrict__ c, float* __restrict__ z, float* __restrict__ u,
        const int* __restrict__ flag)
{
#pragma clang fp contract(off)
    if (*flag == 0) return;
    const int tid = blockIdx.x * 256 + threadIdx.x;
    for (int i = tid; i < NEL; i += NTHREADS_TOT) {
        const float cnv = cn[i];
        const float uv = u[i];
        const float zi = cnv + uv;
        float zm = fabsf(zi) - 0.1f;
        zm = fmaxf(zm, 0.0f);
        const float zn = (zi > 0.0f) ? zm : ((zi < 0.0f) ? -zm : 0.0f);
        c[i] = cnv;
        z[i] = zn;
        u[i] = uv + (cnv - zn);
    }
}

__global__ __launch_bounds__(256) void k_final_rows(const float* __restrict__ c0,
        const float* __restrict__ cA, const float* __restrict__ cB,
        const int* __restrict__ sel, float* __restrict__ outp)
{
#pragma clang fp contract(off)
    __shared__ double sm[256];
    const float* __restrict__ c = (*sel) ? cB : cA;
    const int row = blockIdx.x;
    const size_t base = (size_t)row * D;
    float tv[8];
    double s1 = 0.0;
    #pragma unroll
    for (int s = 0; s < 8; ++s) {
        const int j = threadIdx.x + s * 256;
        const float s0 = c0[base + j];
        const float delta = c[base + j] - s0;
        const float sym = rintf(delta * 10.0f) / 10.0f;
        const float tval = s0 + sym;
        tv[s] = tval;
        s1 += (double)tval;
    }
    const double tot = blk_reduce(s1, sm);
    const float m = (float)(tot / (double)D);
    double s2 = 0.0;
    #pragma unroll
    for (int s = 0; s < 8; ++s) {
        const float dev = tv[s] - m;
        s2 += (double)(dev * dev);
    }
    const double tot2 = blk_reduce(s2, sm);
    const float n = sqrtf((float)tot2);
    const float scale = fminf(1.0f, 10.0f / (n + 1e-8f));
    #pragma unroll
    for (int s = 0; s < 8; ++s) {
        const int j = threadIdx.x + s * 256;
        outp[base + j] = m + (tv[s] - m) * scale;
    }
}

__global__ __launch_bounds__(256) void k_final_glob(const float* __restrict__ c0,
        const float* __restrict__ cA, const float* __restrict__ cB,
        const int* __restrict__ sel, double* __restrict__ partials)
{
    __shared__ double sm[256];
    const float* __restrict__ c = (*sel) ? cB : cA;
    double s3 = 0.0, sd = 0.0;
    const int tid = blockIdx.x * 256 + threadIdx.x;
    for (int i = tid; i < NEL; i += NTHREADS_TOT) {
        const float v = c[i];
        s3 += (double)((v * v) * v);
        const float d = v - c0[i];
        sd += (double)(d * d);
    }
    const double t3 = blk_reduce(s3, sm);
    const double td = blk_reduce(sd, sm);
    if (threadIdx.x == 0) { partials[blockIdx.x] = t3; partials[NBLK + blockIdx.x] = td; }
}

__global__ __launch_bounds__(256) void k_final_status(const double* __restrict__ partials,
        const double* __restrict__ scal, float* __restrict__ outp)
{
    __shared__ double sm[256];
    const int t = threadIdx.x;
    const double a = partials[t] + partials[t+256] + partials[t+512] + partials[t+768];
    const double b = partials[NBLK+t] + partials[NBLK+t+256] + partials[NBLK+t+512] + partials[NBLK+t+768];
    const double t3 = blk_reduce(a, sm);
    const double td = blk_reduce(b, sm);
    if (t == 0) {
        const double chi_cur = t3 / (double)NEL;
        const double diff = sqrt(td);
        const double chi_orig = scal[2];
        const int s_cur = (chi_cur > 0.0) - (chi_cur < 0.0);
        const int s_org = (chi_orig > 0.0) - (chi_orig < 0.0);
        int status;
        if (s_cur != s_org)   status = 2;
        else if (diff > 5.0)  status = 2;
        else if (diff > 1.0)  status = 1;
        else                  status = 0;
        outp[NEL] = (float)status;
    }
}

extern "C" void kernel_launch(void* const* d_in, const int* in_sizes, int n_in,
                              void* d_out, int out_size, void* d_ws, size_t ws_size,
                              hipStream_t stream)
{
    const float* c0 = (const float*)d_in[0];
    const float* W  = (const float*)d_in[1];
    const float* lw = (const float*)d_in[2];
    const float* lb = (const float*)d_in[3];
    float* outp = (float*)d_out;

    const size_t M4 = (size_t)D * D;    // 4M floats
    const size_t N4 = (size_t)NEL;      // 2M floats
    float* Mb = (float*)d_ws;
    float* region = Mb + M4;

    const size_t tail_bytes = (2 * NBLK + 8) * sizeof(double) + 4 * sizeof(int);
    const bool pp = ws_size >= (M4 + 6 * N4) * sizeof(float) + tail_bytes;

    float *cA, *cB, *z, *u, *P0, *P1;
    if (pp) { cA = region; cB = cA + N4; z = cB + N4; u = z + N4; P0 = u + N4; P1 = P0 + N4; }
    else    { cA = region; cB = cA;      z = cA + N4; u = z + N4; P0 = u + N4; P1 = P0 + N4; }
    double* partials = (double*)(P1 + N4);
    double* scal = partials + 2 * NBLK;
    int* flag = (int*)(scal + 8);
    int* frz  = flag + 1;
    int* sel  = frz + 1;

    // M = (W-I)(W^T-I) = W W^T + I - W - W^T, full-K fused epilogue (R1-exact bits)
    k_gemm<<<dim3(D / GN, D / GM, 1), 256, 0, stream>>>(W, W, Mb, Mb, W, D, 0, nullptr);
    k_init<<<NBLK, 256, 0, stream>>>(c0, cA, z, u, partials);
    k_decide0<<<1, 256, 0, stream>>>(partials, scal, flag, frz, sel);

    for (int t = 0; t < 20; ++t) {
        const float* ccur = (pp && (t & 1)) ? cB : cA;
        float* cnxt = (pp && !(t & 1)) ? cB : cA;
        k_gemm<<<dim3(D / GN, BROWS / GM, 2), 256, 0, stream>>>(ccur, Mb, P0, P1, nullptr, D / 2, 1, frz);
        if (pp) {
            k_elem_pp<<<NBLK, 256, 0, stream>>>(P0, P1, ccur, cnxt, z, u, lw, lb, partials, frz);
            k_decide<<<1, 256, 0, stream>>>(partials, scal, flag, frz, sel, (t + 1) & 1);
        } else {
            k_elem<<<NBLK, 256, 0, stream>>>(P0, P1, cA, z, u, lw, lb, partials, frz);
            k_decide<<<1, 256, 0, stream>>>(partials, scal, flag, frz, sel, 0);
            k_commit<<<NBLK, 256, 0, stream>>>(P0, cA, z, u, flag);
        }
    }

    k_final_rows<<<BROWS, 256, 0, stream>>>(c0, cA, cB, sel, outp);
    k_final_glob<<<NBLK, 256, 0, stream>>>(c0, cA, cB, sel, partials);
    k_final_status<<<1, 256, 0, stream>>>(partials, scal, outp);
}